// Round 7
// baseline (253.312 us; speedup 1.0000x reference)
//
#include <hip/hip_runtime.h>
#include <hip/hip_bf16.h>

typedef short bf16x8 __attribute__((ext_vector_type(8)));
typedef float f32x4 __attribute__((ext_vector_type(4)));

#define B_TOT 32768
#define ROWS  64            // 8 batches per WG
#define NTHR  256           // 4 waves; wave w owns rows 16w..16w+15

// ---- workspace layout (elements): bf16 W^T, written by prep_w each call ----
#define WSQ_ELT  0          // ushort [384][256]  qkv_w^T
#define WSP_ELT  98304      // ushort [256][128]  proj_w^T

// ---- main-kernel LDS layout (bytes): total 40704 -> 4 WG/CU ----
#define WQ_STR   136
#define QK_STR   104
#define CH_STR   36         // f32 stride of 32-col epilogue chunk
#define WQ_OFF   0          // ushort[96][136]   26112
#define QK_OFF   26112      // ushort[64][104]   13312 (chunk float[64][36]=9216 overlays)
#define BIAS_OFF 39424      // float[8][8][5]     1280
#define LDS_BYTES 40704     // <=40960 -> 4 WG/CU x 4 waves = 16 waves/CU

static __device__ __forceinline__ unsigned short f2b(float f) {
    __hip_bfloat16 h = __float2bfloat16(f);   // RNE; pairs fuse to v_cvt_pk_bf16_f32
    return reinterpret_cast<unsigned short&>(h);
}
static __device__ __forceinline__ float b2f(unsigned short u) {
    union { unsigned u; float f; } v; v.u = ((unsigned)u) << 16; return v.f;
}

// ---------- pre-kernel: W (f32, row-major) -> W^T (bf16) in ws ----------
__global__ __launch_bounds__(256)
void prep_w(const float* __restrict__ qkv_w, const float* __restrict__ proj_w,
            unsigned short* __restrict__ ws)
{
    __shared__ float tile[64][65];
    const int bid = blockIdx.x;
    const float* src; unsigned short* dst; int ldw, ldk, tr0, tc0;
    if (bid < 24) {            // qkv: 4 k-tiles x 6 c-tiles
        int kr = bid / 6, cg = bid % 6;
        src = qkv_w; dst = ws + WSQ_ELT; ldw = 384; ldk = 256;
        tr0 = kr * 64; tc0 = cg * 64;
    } else {                   // proj: 2 k-tiles x 4 c-tiles
        int b = bid - 24; int kr = b / 4, cg = b % 4;
        src = proj_w; dst = ws + WSP_ELT; ldw = 256; ldk = 128;
        tr0 = kr * 64; tc0 = cg * 64;
    }
    const int t = threadIdx.x;
    #pragma unroll
    for (int i = 0; i < 16; ++i) {
        int idx = i * 256 + t;
        int r = idx >> 6, c = idx & 63;
        tile[r][c] = src[(size_t)(tr0 + r) * ldw + tc0 + c];
    }
    __syncthreads();
    #pragma unroll
    for (int i = 0; i < 2; ++i) {
        int idx = i * 256 + t;          // 0..511
        int c = idx >> 3, r0 = (idx & 7) * 8;
        union { unsigned short u[8]; uint4 v; } pk;
        #pragma unroll
        for (int j = 0; j < 8; ++j) pk.u[j] = f2b(tile[r0 + j][c]);
        *(uint4*)&dst[(size_t)(tc0 + c) * ldk + tr0 + r0] = pk.v;
    }
}

// ---------- main fused kernel ----------
__global__ __launch_bounds__(NTHR, 4)    // cap 128 regs (natural use ~104) -> 16 waves/CU
void ta_fused(const float* __restrict__ x,
              const unsigned short* __restrict__ ws,
              const float* __restrict__ proj_b,
              const float* __restrict__ bias_table,
              const int* __restrict__ rel_index,
              float* __restrict__ out)
{
    __shared__ __align__(16) char smem[LDS_BYTES];
    unsigned short* wqs = (unsigned short*)(smem + WQ_OFF);
    unsigned short* qks = (unsigned short*)(smem + QK_OFF);
    float* chunk  = (float*)(smem + QK_OFF);      // overlays qks (dead in GEMM2)
    float* bias_s = (float*)(smem + BIAS_OFF);

    const unsigned short* wsq = ws + WSQ_ELT;
    const unsigned short* wsp = ws + WSP_ELT;

    const int tid = threadIdx.x;
    const int l   = tid & 63;
    const int w   = tid >> 6;          // 0..3
    const int l15 = l & 15;
    const int l4  = l >> 4;
    const long wg = blockIdx.x;

    // ---- x A-fragments straight to registers (16 rows per wave) ----
    bf16x8 af[8];
    {
        const float* xr = x + wg * (size_t)(ROWS * 256) + (size_t)(16 * w + l15) * 256;
        #pragma unroll
        for (int s = 0; s < 8; ++s) {
            f32x4 d0 = *(const f32x4*)(xr + s * 32 + l4 * 8);
            f32x4 d1 = *(const f32x4*)(xr + s * 32 + l4 * 8 + 4);
            union { unsigned short u[8]; bf16x8 v; } pk;
            #pragma unroll
            for (int j = 0; j < 4; ++j) pk.u[j] = f2b(d0[j]);
            #pragma unroll
            for (int j = 0; j < 4; ++j) pk.u[4 + j] = f2b(d1[j]);
            af[s] = pk.v;
        }
    }
    // ---- bias table ----
    {
        int n = tid >> 5, m = (tid >> 2) & 7, hh = tid & 3;
        int ri = rel_index[n * 8 + m];
        bias_s[n * 40 + m * 5 + hh] = bias_table[ri * 4 + hh];
    }

    bf16x8 of0, of1, of2, of3;
    const f32x4 zero4 = {0.f, 0.f, 0.f, 0.f};

    #pragma unroll 1
    for (int h = 0; h < 4; ++h) {
        f32x4 acc[6];
        #pragma unroll
        for (int i = 0; i < 6; ++i) acc[i] = zero4;

        #pragma unroll
        for (int c = 0; c < 2; ++c) {
            __syncthreads();            // previous stage's wqs readers done
            // stage qkv_w^T slice: 96 rows x 128 k (L2-hot)
            #pragma unroll
            for (int u = 0; u < 6; ++u) {
                int idx = u * NTHR + tid;          // 0..1535
                int rr = idx >> 4, seg = idx & 15;
                int p = rr >> 5, wi = rr & 31;
                uint4 d = *(const uint4*)&wsq[(size_t)(p * 128 + h * 32 + wi) * 256 + c * 128 + seg * 8];
                *(uint4*)&wqs[rr * WQ_STR + seg * 8] = d;
            }
            __syncthreads();            // wqs writes visible
            #pragma unroll
            for (int ks2 = 0; ks2 < 4; ++ks2) {
                bf16x8 a = af[c * 4 + ks2];
                #pragma unroll
                for (int ct = 0; ct < 6; ++ct) {
                    bf16x8 b = *(bf16x8*)&wqs[(ct * 16 + l15) * WQ_STR + ks2 * 32 + l4 * 8];
                    acc[ct] = __builtin_amdgcn_mfma_f32_16x16x32_bf16(a, b, acc[ct], 0, 0, 0);
                }
            }
        }
        // this head's q|k|v -> wave-private qks rows (in-order DS per wave: no barrier)
        #pragma unroll
        for (int ct = 0; ct < 6; ++ct)
          #pragma unroll
          for (int j = 0; j < 4; ++j) {
              int row = 16 * w + l4 * 4 + j;
              qks[row * QK_STR + ct * 16 + l15] = f2b(acc[ct][j]);
          }

        // ---- attention (head h): lane = (row l15 of wave tile, d-slice l4) ----
        {
            const int r  = 16 * w + l15;
            const int rb = r & ~7;
            const int n  = r & 7;
            float qf[8];
            {
                bf16x8 qv = *(bf16x8*)&qks[r * QK_STR + l4 * 8];
                #pragma unroll
                for (int j = 0; j < 8; ++j) qf[j] = b2f((unsigned short)qv[j]);
            }
            float sp[8];
            #pragma unroll
            for (int m = 0; m < 8; ++m) {
                bf16x8 kv = *(bf16x8*)&qks[(rb + m) * QK_STR + 32 + l4 * 8];
                float s = 0.f;
                #pragma unroll
                for (int j = 0; j < 8; ++j) s += qf[j] * b2f((unsigned short)kv[j]);
                sp[m] = s;
            }
            #pragma unroll
            for (int m = 0; m < 8; ++m) {
                sp[m] += __shfl_xor(sp[m], 16);
                sp[m] += __shfl_xor(sp[m], 32);
            }
            float mx = -1e30f;
            #pragma unroll
            for (int m = 0; m < 8; ++m) {
                sp[m] = sp[m] * 0.125f + bias_s[n * 40 + m * 5 + h];
                mx = fmaxf(mx, sp[m]);
            }
            float sum = 0.f;
            #pragma unroll
            for (int m = 0; m < 8; ++m) { sp[m] = __expf(sp[m] - mx); sum += sp[m]; }
            float inv = 1.f / sum;
            float o[8] = {0.f,0.f,0.f,0.f,0.f,0.f,0.f,0.f};
            #pragma unroll
            for (int m = 0; m < 8; ++m) {
                bf16x8 vv = *(bf16x8*)&qks[(rb + m) * QK_STR + 64 + l4 * 8];
                #pragma unroll
                for (int j = 0; j < 8; ++j) o[j] += sp[m] * b2f((unsigned short)vv[j]);
            }
            bf16x8 ofr;
            #pragma unroll
            for (int j = 0; j < 8; ++j) ofr[j] = (short)f2b(o[j] * inv);
            if      (h == 0) of0 = ofr;
            else if (h == 1) of1 = ofr;
            else if (h == 2) of2 = ofr;
            else             of3 = ofr;
        }
    }

    // ---- GEMM2 + fused epilogue, 64 cols per cc, stores in 32-col halves ----
    #pragma unroll 1
    for (int cc = 0; cc < 4; ++cc) {
        __syncthreads();                // prev wqs readers done (incl. GEMM1's last stage)
        #pragma unroll
        for (int u = 0; u < 4; ++u) {
            int idx = u * NTHR + tid;   // 0..1023
            int rr = idx >> 4, seg = idx & 15;
            uint4 d = *(const uint4*)&wsp[(size_t)(cc * 64 + rr) * 128 + seg * 8];
            *(uint4*)&wqs[rr * WQ_STR + seg * 8] = d;
        }
        __syncthreads();                // wqs ready

        f32x4 acc2[4];
        #pragma unroll
        for (int i = 0; i < 4; ++i) acc2[i] = zero4;
        #pragma unroll
        for (int ctl = 0; ctl < 4; ++ctl) {
            #pragma unroll
            for (int ks = 0; ks < 4; ++ks) {
                bf16x8 b = *(bf16x8*)&wqs[(ctl * 16 + l15) * WQ_STR + ks * 32 + l4 * 8];
                bf16x8 a = (ks == 0) ? of0 : (ks == 1) ? of1 : (ks == 2) ? of2 : of3;
                acc2[ctl] = __builtin_amdgcn_mfma_f32_16x16x32_bf16(a, b, acc2[ctl], 0, 0, 0);
            }
        }
        // epilogue in two 32-col halves through LDS chunk (overlays qks)
        #pragma unroll
        for (int hc = 0; hc < 2; ++hc) {
            __syncthreads();            // prev chunk readers done (and, at cc=0,hc=0, attn qks reads)
            #pragma unroll
            for (int c2 = 0; c2 < 2; ++c2) {
                int ctl = hc * 2 + c2;
                float pbv = proj_b[cc * 64 + ctl * 16 + l15];   // 1KB table, L1/L2-hot
                #pragma unroll
                for (int j = 0; j < 4; ++j) {
                    int row = 16 * w + l4 * 4 + j;
                    chunk[row * CH_STR + c2 * 16 + l15] = acc2[ctl][j] + pbv;
                }
            }
            __syncthreads();            // chunk ready
            float* og = out + wg * (size_t)(ROWS * 256) + cc * 64 + hc * 32;
            #pragma unroll
            for (int i = 0; i < 2; ++i) {
                int f0 = i * NTHR + tid;          // 0..511 f32x4-chunks
                int row = f0 >> 3, c4 = f0 & 7;
                f32x4 v = *(f32x4*)&chunk[row * CH_STR + c4 * 4];
                *(f32x4*)(og + (size_t)row * 256 + c4 * 4) = v;
            }
        }
    }
}

extern "C" void kernel_launch(void* const* d_in, const int* in_sizes, int n_in,
                              void* d_out, int out_size, void* d_ws, size_t ws_size,
                              hipStream_t stream)
{
    (void)in_sizes; (void)n_in; (void)ws_size; (void)out_size;
    const float* x  = (const float*)d_in[0];
    const float* qw = (const float*)d_in[1];
    const float* pw = (const float*)d_in[2];
    const float* pb = (const float*)d_in[3];
    const float* bt = (const float*)d_in[4];
    const int*   ri = (const int*)d_in[5];
    float* o = (float*)d_out;
    unsigned short* ws = (unsigned short*)d_ws;

    hipLaunchKernelGGL(prep_w, dim3(32), dim3(256), 0, stream, qw, pw, ws);
    hipLaunchKernelGGL(ta_fused, dim3(B_TOT / 8), dim3(NTHR), 0, stream,
                       x, ws, pb, bt, ri, o);
}